// Round 13
// baseline (497.543 us; speedup 1.0000x reference)
//
#include <hip/hip_runtime.h>

#define USER_NUM 100000
#define ITEM_NUM 50000
#define DD 64
#define NEDGE 3200000
#define NB 16384
#define NSLOT 256

#define ATILE 4096
#define NTILE ((NEDGE + ATILE - 1) / ATILE)      // 782
#define USH 9                                    // user coarse bucket = 512 dests
#define ISH 8                                    // item coarse bucket = 256 dests
#define UBK ((USER_NUM + (1 << USH) - 1) >> USH) // 196
#define IBK ((ITEM_NUM + (1 << ISH) - 1) >> ISH) // 196
#define NBK (UBK + IBK)                          // 392
#define CPAD 16                                  // cursor padding: 1 int per 64B line
#define HIST_GRID 784
#define UHALF (USER_NUM / 2)                     // I-direction source split point
#define BCAP 18432                               // binB LDS staging (mean 16384 +16 sigma)
#define IVCAP 1024                               // per-wave iv staging (item mean 512 +22s)

// group-level longest-first schedule
#define NGRP_U (USER_NUM / 8)    // 12500
#define NGRP_I (ITEM_NUM / 8)    // 6250
#define NGRP (NGRP_U + NGRP_I)   // 18750
#define GBINS 512
#define GPR 2048                 // groups per gperm_scatter block

#define FP8_SCALE 64.0f   // all fp8 tables hold value*64 (avoids e4m3 subnormals)

typedef float v2f __attribute__((ext_vector_type(2)));

__device__ __forceinline__ float waveReduceSum(float x) {
#pragma unroll
    for (int off = 32; off > 0; off >>= 1)
        x += __shfl_down(x, off, 64);
    return x;
}

__device__ __forceinline__ unsigned roundbf(unsigned y) {  // fp32 bits -> bf16 bits (RNE)
    return (y + 0x7fffu + ((y >> 16) & 1u)) >> 16;
}

// ---- fp8 e4m3 helpers (HW cvt; 8 fp8 in a uint2) ----
__device__ __forceinline__ void dec8(const uint2 b, float* f) {
    v2f f0 = __builtin_amdgcn_cvt_pk_f32_fp8(b.x, false);
    v2f f1 = __builtin_amdgcn_cvt_pk_f32_fp8(b.x, true);
    v2f f2 = __builtin_amdgcn_cvt_pk_f32_fp8(b.y, false);
    v2f f3 = __builtin_amdgcn_cvt_pk_f32_fp8(b.y, true);
    f[0] = f0.x; f[1] = f0.y; f[2] = f1.x; f[3] = f1.y;
    f[4] = f2.x; f[5] = f2.y; f[6] = f3.x; f[7] = f3.y;
}
// packed-fma variant: a[4] are float2 accumulators -> v_pk_fma_f32
__device__ __forceinline__ void fma8p(const uint2 b, const float v, v2f* a) {
    v2f f0 = __builtin_amdgcn_cvt_pk_f32_fp8(b.x, false);
    v2f f1 = __builtin_amdgcn_cvt_pk_f32_fp8(b.x, true);
    v2f f2 = __builtin_amdgcn_cvt_pk_f32_fp8(b.y, false);
    v2f f3 = __builtin_amdgcn_cvt_pk_f32_fp8(b.y, true);
    const v2f vv = {v, v};
    a[0] += vv * f0;
    a[1] += vv * f1;
    a[2] += vv * f2;
    a[3] += vv * f3;
}
__device__ __forceinline__ uint2 pack_fp8x8(const float* a) {
    int lo = 0, hi = 0;
    lo = __builtin_amdgcn_cvt_pk_fp8_f32(a[0], a[1], lo, false);
    lo = __builtin_amdgcn_cvt_pk_fp8_f32(a[2], a[3], lo, true);
    hi = __builtin_amdgcn_cvt_pk_fp8_f32(a[4], a[5], hi, false);
    hi = __builtin_amdgcn_cvt_pk_fp8_f32(a[6], a[7], hi, true);
    return make_uint2((unsigned)lo, (unsigned)hi);
}

// fp32 table -> fp8 table, scaled by FP8_SCALE. One thread = 8 features.
__global__ void __launch_bounds__(256) cvt8_kernel(
    const float4* __restrict__ src, uint2* __restrict__ dst, int n8) {
    int t = blockIdx.x * blockDim.x + threadIdx.x;
    if (t < n8) {
        float4 a = src[2 * t], b = src[2 * t + 1];
        float f[8] = {a.x * FP8_SCALE, a.y * FP8_SCALE, a.z * FP8_SCALE, a.w * FP8_SCALE,
                      b.x * FP8_SCALE, b.y * FP8_SCALE, b.z * FP8_SCALE, b.w * FP8_SCALE};
        dst[t] = pack_fp8x8(f);
    }
}

// ---------- two-level binned counting sort ----------

__global__ void __launch_bounds__(256) coarse_hist(
    const int4* __restrict__ eu4, const int4* __restrict__ ei4,
    int* __restrict__ coarseCnt) {
    __shared__ int lc[NBK];
    const int t = threadIdx.x;
    for (int j = t; j < NBK; j += 256) lc[j] = 0;
    __syncthreads();
    for (int k = blockIdx.x * 256 + t; k < NEDGE / 4; k += HIST_GRID * 256) {
        int4 u = eu4[k];
        int4 i = ei4[k];
        atomicAdd(&lc[u.x >> USH], 1); atomicAdd(&lc[u.y >> USH], 1);
        atomicAdd(&lc[u.z >> USH], 1); atomicAdd(&lc[u.w >> USH], 1);
        atomicAdd(&lc[UBK + (i.x >> ISH)], 1); atomicAdd(&lc[UBK + (i.y >> ISH)], 1);
        atomicAdd(&lc[UBK + (i.z >> ISH)], 1); atomicAdd(&lc[UBK + (i.w >> ISH)], 1);
    }
    __syncthreads();
    for (int j = t; j < NBK; j += 256)
        if (lc[j]) atomicAdd(&coarseCnt[j * CPAD], lc[j]);
}

__global__ void __launch_bounds__(512) coarse_scan(
    const int* __restrict__ cnt, int* __restrict__ base, int* __restrict__ cur) {
    __shared__ int a[512];
    const int t = threadIdx.x;
    int v = (t < UBK) ? cnt[t * CPAD] : 0;
    a[t] = v;
    __syncthreads();
    for (int off = 1; off < 512; off <<= 1) {
        int x = (t >= off) ? a[t - off] : 0;
        __syncthreads();
        a[t] += x;
        __syncthreads();
    }
    if (t < UBK) { base[t] = a[t] - v; cur[t * CPAD] = a[t] - v; }
    __syncthreads();
    v = (t < IBK) ? cnt[(UBK + t) * CPAD] : 0;
    a[t] = v;
    __syncthreads();
    for (int off = 1; off < 512; off <<= 1) {
        int x = (t >= off) ? a[t - off] : 0;
        __syncthreads();
        a[t] += x;
        __syncthreads();
    }
    if (t < IBK) { base[UBK + t] = a[t] - v; cur[(UBK + t) * CPAD] = a[t] - v; }
}

// binA: block-level LDS counting sort per (tile, direction). Payload is built
// and sorted entirely in LDS, then flushed sequentially so global writes are
// wave-coalesced full lines. ATILE=4096 -> 40960B LDS -> exactly 4 blocks/CU.
// blockIdx.y: 0 = U-direction, 1 = I-direction.
__global__ void __launch_bounds__(256, 4) binA(
    const int* __restrict__ eu, const int* __restrict__ ei,
    const float* __restrict__ ev,
    int* __restrict__ ccur,           // padded cursors, NBK*CPAD
    int2* __restrict__ stU, int2* __restrict__ stI) {
    __shared__ int2 pay[ATILE];             // 32 KB sorted payload
    __shared__ unsigned char sbid[ATILE];   // 4 KB bucket id per slot
    __shared__ int hist[256];
    __shared__ int pscan[256];
    __shared__ int cursor[256];
    __shared__ int delta[256];

    const int t = threadIdx.x;
    const int dirI = blockIdx.y;
    const int tb = blockIdx.x * ATILE;
    const int n = min(ATILE, NEDGE - tb);
    const int* key = dirI ? ei : eu;
    const int SH = dirI ? ISH : USH;

    hist[t] = 0;
    __syncthreads();
    for (int k = t; k < n; k += 256)
        atomicAdd(&hist[key[tb + k] >> SH], 1);
    __syncthreads();
    pscan[t] = hist[t];
    __syncthreads();
    for (int off = 1; off < 256; off <<= 1) {
        int x = (t >= off) ? pscan[t - off] : 0;
        __syncthreads();
        pscan[t] += x;
        __syncthreads();
    }
    {
        const int c = hist[t];
        const int lst = pscan[t] - c;
        cursor[t] = lst;
        int gp = 0;
        if (c > 0) {
            int* gc = dirI ? (ccur + UBK * CPAD) : ccur;
            gp = atomicAdd(&gc[t * CPAD], c);
        }
        delta[t] = gp - lst;
    }
    __syncthreads();
    // scatter payload into sorted LDS slots; edge stream read is linear
    if (dirI == 0) {
        for (int k = t; k < n; k += 256) {
            const int e = tb + k;
            const int u = eu[e], i = ei[e];
            const int b = u >> USH;
            const int p = atomicAdd(&cursor[b], 1);
            pay[p] = make_int2(((u & ((1 << USH) - 1)) << 16) | i,
                               __float_as_int(ev[e]));
            sbid[p] = (unsigned char)b;
        }
    } else {
        for (int k = t; k < n; k += 256) {
            const int e = tb + k;
            const int u = eu[e], i = ei[e];
            const int b = i >> ISH;
            const int p = atomicAdd(&cursor[b], 1);
            pay[p] = make_int2(((i & ((1 << ISH) - 1)) << 17) | u,
                               __float_as_int(ev[e]));
            sbid[p] = (unsigned char)b;
        }
    }
    __syncthreads();
    // sequential flush: consecutive threads -> consecutive global addresses
    int2* st = dirI ? stI : stU;
    for (int p = t; p < n; p += 256)
        st[delta[sbid[p]] + p] = pay[p];
}

// binB: fine sort within each coarse bucket. Item branch keeps the R6
// source-split key (local_item<<1)|(u>=UHALF); rpIm = mid pointer. Final
// placement scatters into a 72KB LDS staging buffer then flushes
// sequentially (coalesced full-line writes). Fallback to direct scatter if
// a bucket exceeds BCAP (+16 sigma; data-dependent only, capture-safe).
__global__ void __launch_bounds__(256) binB(
    const int2* __restrict__ stU, const int2* __restrict__ stI,
    const int* __restrict__ base, const int* __restrict__ cnt,
    int* __restrict__ rpU, int* __restrict__ rpI, int* __restrict__ rpIm,
    unsigned* __restrict__ ivU, unsigned* __restrict__ ivI) {
    __shared__ int h[512];
    __shared__ unsigned pay[BCAP];   // 72 KB
    const int t = threadIdx.x;
    const int b = blockIdx.x;
    if (b < UBK) {
        const int s = base[b], n = cnt[b * CPAD];
        const int dbase = b << USH;
        h[t] = 0; h[t + 256] = 0;
        __syncthreads();
        for (int p = s + t; p < s + n; p += 256)
            atomicAdd(&h[(unsigned)stU[p].x >> 16], 1);
        __syncthreads();
        const int o0 = h[t], o1 = h[t + 256];
        for (int off = 1; off < 512; off <<= 1) {
            int x0 = (t >= off) ? h[t - off] : 0;
            int x1 = (t + 256 >= off) ? h[t + 256 - off] : 0;
            __syncthreads();
            h[t] += x0; h[t + 256] += x1;
            __syncthreads();
        }
        const int e0 = h[t] - o0, e1 = h[t + 256] - o1;   // bucket-relative
        __syncthreads();
        h[t] = e0; h[t + 256] = e1;
        if (dbase + t < USER_NUM) rpU[dbase + t] = s + e0;
        if (dbase + 256 + t < USER_NUM) rpU[dbase + 256 + t] = s + e1;
        if (t == 0 && dbase + 512 >= USER_NUM) rpU[USER_NUM] = s + n;
        __syncthreads();
        if (n <= BCAP) {
            for (int p = s + t; p < s + n; p += 256) {
                int2 en = stU[p];
                unsigned x = (unsigned)en.x;
                int pos = atomicAdd(&h[x >> 16], 1);
                unsigned bf = roundbf((unsigned)en.y);
                pay[pos] = (bf << 16) | (x & 0xFFFFu);
            }
            __syncthreads();
            for (int k = t; k < n; k += 256) ivU[s + k] = pay[k];
        } else {
            for (int p = s + t; p < s + n; p += 256) {
                int2 en = stU[p];
                unsigned x = (unsigned)en.x;
                int pos = atomicAdd(&h[x >> 16], 1);
                unsigned bf = roundbf((unsigned)en.y);
                ivU[s + pos] = (bf << 16) | (x & 0xFFFFu);
            }
        }
    } else {
        const int ib = b - UBK;
        const int s = base[b], n = cnt[b * CPAD];
        const int dbase = ib << ISH;
        h[t] = 0; h[t + 256] = 0;
        __syncthreads();
        for (int p = s + t; p < s + n; p += 256) {
            unsigned x = (unsigned)stI[p].x;
            const int c = (int)((x >> 17) << 1) | (((x & 0x1FFFFu) >= UHALF) ? 1 : 0);
            atomicAdd(&h[c], 1);
        }
        __syncthreads();
        // counts of my interleaved pair (row t: counters 2t, 2t+1)
        const int c0 = h[2 * t], c1 = h[2 * t + 1];
        // inclusive scan over 512 linear slots (thread owns slots t, t+256);
        // linear order == final layout order (row-major, half0 then half1)
        for (int off = 1; off < 512; off <<= 1) {
            int x0 = (t >= off) ? h[t - off] : 0;
            int x1 = (t + 256 >= off) ? h[t + 256 - off] : 0;
            __syncthreads();
            h[t] += x0; h[t + 256] += x1;
            __syncthreads();
        }
        const int incl0 = h[2 * t], incl1 = h[2 * t + 1];
        const int st0 = incl0 - c0;      // bucket-relative half0 start
        const int st1 = incl1 - c1;      // bucket-relative half1 start
        __syncthreads();
        h[2 * t] = st0; h[2 * t + 1] = st1;  // cursors for scatter
        if (dbase + t < ITEM_NUM) { rpI[dbase + t] = s + st0; rpIm[dbase + t] = s + st1; }
        if (t == 0 && dbase + 256 >= ITEM_NUM) rpI[ITEM_NUM] = s + n;
        __syncthreads();
        if (n <= BCAP) {
            for (int p = s + t; p < s + n; p += 256) {
                int2 en = stI[p];
                unsigned x = (unsigned)en.x;
                const int c = (int)((x >> 17) << 1) | (((x & 0x1FFFFu) >= UHALF) ? 1 : 0);
                int pos = atomicAdd(&h[c], 1);
                unsigned v15 = roundbf((unsigned)en.y) & 0x7FFFu;
                pay[pos] = (v15 << 17) | (x & 0x1FFFFu);
            }
            __syncthreads();
            for (int k = t; k < n; k += 256) ivI[s + k] = pay[k];
        } else {
            for (int p = s + t; p < s + n; p += 256) {
                int2 en = stI[p];
                unsigned x = (unsigned)en.x;
                const int c = (int)((x >> 17) << 1) | (((x & 0x1FFFFu) >= UHALF) ? 1 : 0);
                int pos = atomicAdd(&h[c], 1);
                unsigned v15 = roundbf((unsigned)en.y) & 0x7FFFu;
                ivI[s + pos] = (v15 << 17) | (x & 0x1FFFFu);
            }
        }
    }
}

// ---------- group-level longest-first schedule ----------
// A "group" = the 8 consecutive rows one wave processes (R9 structure,
// unchanged internally). gperm sorts groups by descending edge weight so
// straggler groups run FIRST (LPT scheduling): the drain tail collapses
// without touching any memory layout (R7's row-perm FETCH penalty cannot
// recur). Heavier item groups naturally sort ahead of user groups.

__device__ __forceinline__ int group_weight(
    int g, const int* __restrict__ rpU, const int* __restrict__ rpI) {
    if (g < NGRP_U) return rpU[g * 8 + 8] - rpU[g * 8];
    const int rb = (g - NGRP_U) * 8;
    return rpI[rb + 8] - rpI[rb];
}
__device__ __forceinline__ int group_bin(int w) {
    return (GBINS - 1) - min(w >> 1, GBINS - 1);   // heavier -> smaller bin
}

__global__ void __launch_bounds__(256) gperm_hist(
    const int* __restrict__ rpU, const int* __restrict__ rpI,
    int* __restrict__ bins) {                      // GBINS ints, zeroed
    __shared__ int lb[GBINS];
    const int t = threadIdx.x;
    for (int j = t; j < GBINS; j += 256) lb[j] = 0;
    __syncthreads();
    for (int g = blockIdx.x * 256 + t; g < NGRP; g += gridDim.x * 256)
        atomicAdd(&lb[group_bin(group_weight(g, rpU, rpI))], 1);
    __syncthreads();
    for (int j = t; j < GBINS; j += 256)
        if (lb[j]) atomicAdd(&bins[j], lb[j]);
}

__global__ void __launch_bounds__(512) gperm_scan(
    const int* __restrict__ bins, int* __restrict__ gcur) {  // gcur: GBINS*CPAD
    __shared__ int a[GBINS];
    const int t = threadIdx.x;
    int v = bins[t];
    a[t] = v;
    __syncthreads();
    for (int off = 1; off < GBINS; off <<= 1) {
        int x = (t >= off) ? a[t - off] : 0;
        __syncthreads();
        a[t] += x;
        __syncthreads();
    }
    gcur[t * CPAD] = a[t] - v;                     // exclusive prefix
}

__global__ void __launch_bounds__(256) gperm_scatter(
    const int* __restrict__ rpU, const int* __restrict__ rpI,
    int* __restrict__ gcur, int* __restrict__ gperm) {
    __shared__ int lh[GBINS], lcur[GBINS], ldelta[GBINS];
    const int t = threadIdx.x;
    const int g0 = blockIdx.x * GPR;
    for (int j = t; j < GBINS; j += 256) { lh[j] = 0; lcur[j] = 0; }
    __syncthreads();
    for (int k = t; k < GPR; k += 256) {
        const int g = g0 + k;
        if (g < NGRP)
            atomicAdd(&lh[group_bin(group_weight(g, rpU, rpI))], 1);
    }
    __syncthreads();
    for (int j = t; j < GBINS; j += 256) {
        const int c = lh[j];
        ldelta[j] = c ? atomicAdd(&gcur[j * CPAD], c) : 0;
    }
    __syncthreads();
    for (int k = t; k < GPR; k += 256) {
        const int g = g0 + k;
        if (g < NGRP) {
            const int bin = group_bin(group_weight(g, rpU, rpI));
            const int rank = atomicAdd(&lcur[bin], 1);
            gperm[ldelta[bin] + rank] = g;
        }
    }
}

// ---------- gather hop core ----------
// sub-owns-row layout: each 8-lane sub-group processes ONE full row (lane r
// holds features 8r..8r+7), a wave covers one GROUP of 8 consecutive rows,
// selected via gperm (longest-first). Each wave cooperatively stages its
// group's contiguous iv range into LDS (coalesced 256B loads; inner loop
// reads indices via ds_read). I-direction rows run as two ranges
// (u<UHALF, u>=UHALF via rpIm) for per-XCD L2 fit.

template<bool ISU>
__device__ __forceinline__ int xof(unsigned q) {
    return ISU ? (int)(q & 0xFFFFu) : (int)(q & 0x1FFFFu);
}
template<bool ISU>
__device__ __forceinline__ float vof(unsigned q) {
    return ISU ? __uint_as_float(q & 0xFFFF0000u)
               : __uint_as_float((q >> 17) << 16);
}

template<bool ISU, int N>
__device__ __forceinline__ void edge_block(
    const unsigned* __restrict__ iv, int t,
    const uint2* __restrict__ srcr, v2f* a0, v2f* a1) {
    unsigned q[N];
    uint2 b[N];
#pragma unroll
    for (int j = 0; j < N; j++) q[j] = iv[t + j];
#pragma unroll
    for (int j = 0; j < N; j++) b[j] = srcr[xof<ISU>(q[j]) * 8];
#pragma unroll
    for (int j = 0; j < N; j++) fma8p(b[j], vof<ISU>(q[j]), (j & 1) ? a1 : a0);
}

template<bool ISU>
__device__ __forceinline__ void accum_range(
    const unsigned* __restrict__ iv, const uint2* __restrict__ srcr,
    int s, int e2, v2f* a0, v2f* a1) {
    int t = s;
    for (; t + 15 < e2; t += 16) edge_block<ISU, 16>(iv, t, srcr, a0, a1);
    if (t + 7 < e2) { edge_block<ISU, 8>(iv, t, srcr, a0, a1); t += 8; }
    if (t + 3 < e2) { edge_block<ISU, 4>(iv, t, srcr, a0, a1); t += 4; }
    if (t + 1 < e2) { edge_block<ISU, 2>(iv, t, srcr, a0, a1); t += 2; }
    if (t < e2)     edge_block<ISU, 1>(iv, t, srcr, a0, a1);
}

__device__ __forceinline__ void acc_combine(const v2f* a0, const v2f* a1, float* acc) {
#pragma unroll
    for (int k = 0; k < 4; k++) {
        const v2f sv = a0[k] + a1[k];
        acc[2 * k]     = sv.x;
        acc[2 * k + 1] = sv.y;
    }
}

__global__ void __launch_bounds__(256) gather_hop_f8(
    const int* __restrict__ rpU, const unsigned* __restrict__ ivU,
    const uint2* __restrict__ srcForU, uint2* __restrict__ outU,
    const int* __restrict__ rpI, const int* __restrict__ rpIm,
    const unsigned* __restrict__ ivI,
    const uint2* __restrict__ srcForI, uint2* __restrict__ outI,
    const int* __restrict__ gperm) {
    __shared__ unsigned sIv[4][IVCAP];
    const int wslot = threadIdx.x >> 6;
    const int lane = threadIdx.x & 63;
    const int sub = lane >> 3;
    const int r = lane & 7;
    const int wave = blockIdx.x * 4 + wslot;
    const bool active = wave < NGRP;
    int grp = 0;
    if (active) grp = gperm[wave];
    const bool isI = grp >= NGRP_U;
    int rowBase = 0;
    const int* rp = rpU; const unsigned* ivg = ivU;
    if (active) {
        rowBase = isI ? (grp - NGRP_U) * 8 : grp * 8;
        rp  = isI ? rpI : rpU;
        ivg = isI ? ivI : ivU;
    }
    int sB = 0, eB = 0;
    if (active) { sB = rp[rowBase]; eB = rp[rowBase + 8]; }
    unsigned* buf = sIv[wslot];
    const int nst = min(eB - sB, IVCAP);
    for (int k = lane; k < nst; k += 64) buf[k] = ivg[sB + k];
    __syncthreads();
    if (!active) return;
    const int row = rowBase + sub;
    const int sr = rp[row], er = rp[row + 1];
    float acc[8];
    v2f a0[4] = {{0.f,0.f},{0.f,0.f},{0.f,0.f},{0.f,0.f}};
    v2f a1[4] = {{0.f,0.f},{0.f,0.f},{0.f,0.f},{0.f,0.f}};
    if (eB - sB <= IVCAP) {
        const unsigned* p = buf - sB;           // LDS-backed, ds_read path
        if (isI) {
            const int mr = rpIm[row];
            const uint2* srcr = srcForI + r;
            accum_range<false>(p, srcr, sr, mr, a0, a1);
            accum_range<false>(p, srcr, mr, er, a0, a1);
        } else {
            accum_range<true>(p, srcForU + r, sr, er, a0, a1);
        }
    } else {                                     // overflow fallback (never hot)
        if (isI) {
            const int mr = rpIm[row];
            const uint2* srcr = srcForI + r;
            accum_range<false>(ivg, srcr, sr, mr, a0, a1);
            accum_range<false>(ivg, srcr, mr, er, a0, a1);
        } else {
            accum_range<true>(ivg, srcForU + r, sr, er, a0, a1);
        }
    }
    acc_combine(a0, a1, acc);
    if (isI) outI[row * 8 + r] = pack_fp8x8(acc);
    else     outU[row * 8 + r] = pack_fp8x8(acc);
}

// hop3 with fused self-distillation loss (same staging + gperm order).
__global__ void __launch_bounds__(256) gather_hop3(
    const int* __restrict__ rpU, const unsigned* __restrict__ ivU,
    const uint2* __restrict__ srcForU,
    const int* __restrict__ rpI, const int* __restrict__ rpIm,
    const unsigned* __restrict__ ivI, const uint2* __restrict__ srcForI,
    const float4* __restrict__ embU, const uint2* __restrict__ g1u,
    const uint2* __restrict__ g2u, float4* __restrict__ gcnU,
    const float4* __restrict__ embI, const uint2* __restrict__ g1i,
    const uint2* __restrict__ g2i, float4* __restrict__ gcnI,
    const float4* __restrict__ oldU4, const float4* __restrict__ oldI4,
    const float* __restrict__ nU, const float* __restrict__ nI,
    float* __restrict__ accs,
    const int* __restrict__ gperm) {
    __shared__ unsigned sIv[4][IVCAP];
    const int wslot = threadIdx.x >> 6;
    const int lane = threadIdx.x & 63;
    const int sub = lane >> 3;
    const int r = lane & 7;
    const int wave = blockIdx.x * 4 + wslot;
    const bool active = wave < NGRP;
    int grp = 0;
    if (active) grp = gperm[wave];
    const bool isI = grp >= NGRP_U;
    int rowBase = 0;
    const int* rp = rpU; const unsigned* ivg = ivU;
    if (active) {
        rowBase = isI ? (grp - NGRP_U) * 8 : grp * 8;
        rp  = isI ? rpI : rpU;
        ivg = isI ? ivI : ivU;
    }
    int sB = 0, eB = 0;
    if (active) { sB = rp[rowBase]; eB = rp[rowBase + 8]; }
    unsigned* buf = sIv[wslot];
    const int nst = min(eB - sB, IVCAP);
    for (int k = lane; k < nst; k += 64) buf[k] = ivg[sB + k];
    __syncthreads();
    if (!active) return;
    const int row = rowBase + sub;
    const int sr = rp[row], er = rp[row + 1];
    float acc[8];
    v2f a0[4] = {{0.f,0.f},{0.f,0.f},{0.f,0.f},{0.f,0.f}};
    v2f a1[4] = {{0.f,0.f},{0.f,0.f},{0.f,0.f},{0.f,0.f}};
    if (eB - sB <= IVCAP) {
        const unsigned* p = buf - sB;
        if (isI) {
            const int mr = rpIm[row];
            const uint2* srcr = srcForI + r;
            accum_range<false>(p, srcr, sr, mr, a0, a1);
            accum_range<false>(p, srcr, mr, er, a0, a1);
        } else {
            accum_range<true>(p, srcForU + r, sr, er, a0, a1);
        }
    } else {
        if (isI) {
            const int mr = rpIm[row];
            const uint2* srcr = srcForI + r;
            accum_range<false>(ivg, srcr, sr, mr, a0, a1);
            accum_range<false>(ivg, srcr, mr, er, a0, a1);
        } else {
            accum_range<true>(ivg, srcForU + r, sr, er, a0, a1);
        }
    }
    acc_combine(a0, a1, acc);
    {
        const float C1 = 0.5f / FP8_SCALE;
        const float C2 = (1.0f / 3.0f) / FP8_SCALE;
        const float C3 = 0.25f / FP8_SCALE;
        const float4* emb  = isI ? embI : embU;
        const uint2*  g1   = isI ? g1i  : g1u;
        const uint2*  g2   = isI ? g2i  : g2u;
        float4*       gcn  = isI ? gcnI : gcnU;
        const float4* old4 = isI ? oldI4 : oldU4;
        const float*  nrm  = isI ? nI   : nU;
        float f1[8], f2[8];
        dec8(g1[row * 8 + r], f1);
        dec8(g2[row * 8 + r], f2);
        const float4 e0 = emb[row * 16 + 2 * r];
        const float4 e1 = emb[row * 16 + 2 * r + 1];
        float4 o0, o1;
        o0.x = e0.x + C1 * f1[0] + C2 * f2[0] + C3 * acc[0];
        o0.y = e0.y + C1 * f1[1] + C2 * f2[1] + C3 * acc[1];
        o0.z = e0.z + C1 * f1[2] + C2 * f2[2] + C3 * acc[2];
        o0.w = e0.w + C1 * f1[3] + C2 * f2[3] + C3 * acc[3];
        o1.x = e1.x + C1 * f1[4] + C2 * f2[4] + C3 * acc[4];
        o1.y = e1.y + C1 * f1[5] + C2 * f2[5] + C3 * acc[5];
        o1.z = e1.z + C1 * f1[6] + C2 * f2[6] + C3 * acc[6];
        o1.w = e1.w + C1 * f1[7] + C2 * f2[7] + C3 * acc[7];
        gcn[row * 16 + 2 * r] = o0;
        gcn[row * 16 + 2 * r + 1] = o1;
        // ---- fused self-distillation loss ----
        const float4 d0 = old4[row * 16 + 2 * r];
        const float4 d1 = old4[row * 16 + 2 * r + 1];
        const float ex = d0.x - o0.x, ey = d0.y - o0.y;
        const float ez = d0.z - o0.z, ew = d0.w - o0.w;
        const float fx = d1.x - o1.x, fy = d1.y - o1.y;
        const float fz = d1.z - o1.z, fw = d1.w - o1.w;
        float ss = ex * ex + ey * ey + ez * ez + ew * ew
                 + fx * fx + fy * fy + fz * fz + fw * fw;
        ss += __shfl_xor(ss, 1, 64);
        ss += __shfl_xor(ss, 2, 64);
        ss += __shfl_xor(ss, 4, 64);
        float val = (r == 0) ? sqrtf(ss) * nrm[row] : 0.0f;
        val = waveReduceSum(val);
        if (lane == 0) {
            const int slot = wave & (NSLOT - 1);
            unsafeAtomicAdd(&accs[(isI ? 3 : 2) * NSLOT + slot], val);
        }
    }
}

// ---------- losses ----------
__global__ void __launch_bounds__(256) bpr_loss(
    const int* __restrict__ user, const int* __restrict__ itemI,
    const int* __restrict__ itemJ,
    const float4* __restrict__ gcnU4, const float4* __restrict__ gcnI4,
    float* __restrict__ accs) {
    const int lane = threadIdx.x & 63;
    const int sub = lane >> 4;
    const int r = lane & 15;
    const int W = blockIdx.x * 4 + (threadIdx.x >> 6);
    const int NW = gridDim.x * 4;
    float accB = 0.0f, accR = 0.0f;
    for (int g = W; g < NB / 4; g += NW) {
        const int samp = g * 4 + sub;
        const int uu = user[samp], vi = itemI[samp], vj = itemJ[samp];
        const float4 u  = gcnU4[uu * 16 + r];
        const float4 xi = gcnI4[vi * 16 + r];
        const float4 xj = gcnI4[vj * 16 + r];
        float pi = u.x * xi.x + u.y * xi.y + u.z * xi.z + u.w * xi.w;
        float pj = u.x * xj.x + u.y * xj.y + u.z * xj.z + u.w * xj.w;
        float rg = u.x * u.x + u.y * u.y + u.z * u.z + u.w * u.w
                 + xi.x * xi.x + xi.y * xi.y + xi.z * xi.z + xi.w * xi.w
                 + xj.x * xj.x + xj.y * xj.y + xj.z * xj.z + xj.w * xj.w;
#pragma unroll
        for (int off = 1; off <= 8; off <<= 1) {
            pi += __shfl_xor(pi, off, 64);
            pj += __shfl_xor(pj, off, 64);
            rg += __shfl_xor(rg, off, 64);
        }
        if (r == 0) {
            const float x = pi - pj;
            accB += fmaxf(-x, 0.0f) + log1pf(expf(-fabsf(x)));
            accR += rg;
        }
    }
    accB = waveReduceSum(accB);
    accR = waveReduceSum(accR);
    if (lane == 0) {
        const int slot = W & (NSLOT - 1);
        unsafeAtomicAdd(&accs[0 * NSLOT + slot], accB);
        unsafeAtomicAdd(&accs[1 * NSLOT + slot], accR);
    }
}

__global__ void __launch_bounds__(64) finalize(const float* __restrict__ accs,
                                               float* __restrict__ out) {
    const int lane = threadIdx.x;
    float s[4];
#pragma unroll
    for (int k = 0; k < 4; k++) {
        float v = 0.0f;
        for (int j = lane; j < NSLOT; j += 64) v += accs[k * NSLOT + j];
        s[k] = waveReduceSum(v);
    }
    if (lane == 0) {
        const float loss_bpr = s[0] / NB + 1e-4f * (s[1] / NB);
        const float loss_self = s[2] / USER_NUM + s[3] / ITEM_NUM;
        out[0] = loss_bpr;
        out[1] = 100.0f * loss_self;
        out[2] = 1.0f;
        out[3] = 1.0f;
    }
}

extern "C" void kernel_launch(void* const* d_in, const int* in_sizes, int n_in,
                              void* d_out, int out_size, void* d_ws, size_t ws_size,
                              hipStream_t stream) {
    const int*   user     = (const int*)d_in[0];
    const int*   item_i   = (const int*)d_in[1];
    const int*   item_j   = (const int*)d_in[2];
    const int*   edge_u   = (const int*)d_in[3];
    const int*   edge_i   = (const int*)d_in[4];
    const float* edge_val = (const float*)d_in[5];
    const float* user_emb = (const float*)d_in[6];
    const float* item_emb = (const float*)d_in[7];
    const float* old_U    = (const float*)d_in[8];
    const float* old_I    = (const float*)d_in[9];
    const float* n_U      = (const float*)d_in[10];
    const float* n_I      = (const float*)d_in[11];
    float* out = (float*)d_out;

    char* base = (char*)d_ws;
    size_t off = 0;
    auto carve = [&](size_t bytes) {
        char* p = base + off;
        off += (bytes + 255) & ~(size_t)255;
        return p;
    };
    int*      coarseCnt = (int*)carve(NBK * CPAD * 4);  // padded: 1 count / 64B
    float*    accs      = (float*)carve(4 * NSLOT * 4);
    int*      gbins     = (int*)carve(GBINS * 4);       // group-degree bins (zeroed)
    size_t zero_bytes = off;  // everything above must start zeroed
    int*      cbase = (int*)carve(NBK * 4);             // compact
    int*      ccur  = (int*)carve(NBK * CPAD * 4);      // padded cursors
    int*      gcur  = (int*)carve(GBINS * CPAD * 4);    // gperm cursors
    int*      gperm = (int*)carve(NGRP * 4);
    int*      rpU   = (int*)carve((USER_NUM + 1) * 4);
    int*      rpI   = (int*)carve((ITEM_NUM + 1) * 4);
    int*      rpIm  = (int*)carve((ITEM_NUM + 1) * 4);
    unsigned* ivU   = (unsigned*)carve((size_t)NEDGE * 4);
    unsigned* ivI   = (unsigned*)carve((size_t)NEDGE * 4);
    uint2*    ebU8  = (uint2*)carve((size_t)USER_NUM * DD);  // fp8 tables
    uint2*    ebI8  = (uint2*)carve((size_t)ITEM_NUM * DD);
    uint2*    g1u8  = (uint2*)carve((size_t)USER_NUM * DD);
    uint2*    g1i8  = (uint2*)carve((size_t)ITEM_NUM * DD);
    uint2*    g2u8  = (uint2*)carve((size_t)USER_NUM * DD);
    uint2*    g2i8  = (uint2*)carve((size_t)ITEM_NUM * DD);
    int2*     stU   = (int2*)carve((size_t)NEDGE * 8);   // staging, dead after binB
    int2*     stI   = (int2*)carve((size_t)NEDGE * 8);
    float* gcnU = (float*)stU;   // aliases staging (hop3 runs after binB)
    float* gcnI = (float*)stI;

    hipMemsetAsync(d_ws, 0, zero_bytes, stream);

    const dim3 blk(256);

    cvt8_kernel<<<(USER_NUM * 8 + 255) / 256, blk, 0, stream>>>(
        (const float4*)user_emb, ebU8, USER_NUM * 8);
    cvt8_kernel<<<(ITEM_NUM * 8 + 255) / 256, blk, 0, stream>>>(
        (const float4*)item_emb, ebI8, ITEM_NUM * 8);

    coarse_hist<<<HIST_GRID, blk, 0, stream>>>((const int4*)edge_u,
                                               (const int4*)edge_i, coarseCnt);
    coarse_scan<<<1, 512, 0, stream>>>(coarseCnt, cbase, ccur);
    binA<<<dim3(NTILE, 2), blk, 0, stream>>>(edge_u, edge_i, edge_val,
                                             ccur, stU, stI);
    binB<<<NBK, blk, 0, stream>>>(stU, stI, cbase, coarseCnt,
                                  rpU, rpI, rpIm, ivU, ivI);

    gperm_hist<<<32, blk, 0, stream>>>(rpU, rpI, gbins);
    gperm_scan<<<1, 512, 0, stream>>>(gbins, gcur);
    gperm_scatter<<<(NGRP + GPR - 1) / GPR, blk, 0, stream>>>(rpU, rpI,
                                                              gcur, gperm);

    const int hop_grid = (NGRP + 3) / 4;           // 4688

    gather_hop_f8<<<hop_grid, blk, 0, stream>>>(rpU, ivU, ebI8, g1u8,
                                                rpI, rpIm, ivI, ebU8, g1i8,
                                                gperm);
    gather_hop_f8<<<hop_grid, blk, 0, stream>>>(rpU, ivU, g1i8, g2u8,
                                                rpI, rpIm, ivI, g1u8, g2i8,
                                                gperm);
    gather_hop3<<<hop_grid, blk, 0, stream>>>(
        rpU, ivU, g2i8, rpI, rpIm, ivI, g2u8,
        (const float4*)user_emb, g1u8, g2u8, (float4*)gcnU,
        (const float4*)item_emb, g1i8, g2i8, (float4*)gcnI,
        (const float4*)old_U, (const float4*)old_I, n_U, n_I, accs,
        gperm);

    bpr_loss<<<128, blk, 0, stream>>>(user, item_i, item_j,
                                      (const float4*)gcnU, (const float4*)gcnI, accs);
    finalize<<<1, 64, 0, stream>>>(accs, out);
}

// Round 14
// 477.268 us; speedup vs baseline: 1.0425x; 1.0425x over previous
//
#include <hip/hip_runtime.h>

#define USER_NUM 100000
#define ITEM_NUM 50000
#define DD 64
#define NEDGE 3200000
#define NB 16384
#define NSLOT 256

#define ATILE 4096
#define NTILE ((NEDGE + ATILE - 1) / ATILE)      // 782
#define USH 9                                    // user coarse bucket = 512 dests
#define ISH 8                                    // item coarse bucket = 256 dests
#define UBK ((USER_NUM + (1 << USH) - 1) >> USH) // 196
#define IBK ((ITEM_NUM + (1 << ISH) - 1) >> ISH) // 196
#define NBK (UBK + IBK)                          // 392
#define CPAD 16                                  // cursor padding: 1 int per 64B line
#define HIST_GRID 784
#define UHALF (USER_NUM / 2)                     // I-direction source split point
#define BCAP 18432                               // binB LDS staging (mean 16384 +16 sigma)
#define IVCAP 1024                               // per-wave iv staging (item mean 512 +22s)

#define FP8_SCALE 64.0f   // all fp8 tables hold value*64 (avoids e4m3 subnormals)

typedef float v2f __attribute__((ext_vector_type(2)));

__device__ __forceinline__ float waveReduceSum(float x) {
#pragma unroll
    for (int off = 32; off > 0; off >>= 1)
        x += __shfl_down(x, off, 64);
    return x;
}

__device__ __forceinline__ unsigned roundbf(unsigned y) {  // fp32 bits -> bf16 bits (RNE)
    return (y + 0x7fffu + ((y >> 16) & 1u)) >> 16;
}

// ---- fp8 e4m3 helpers (HW cvt; 8 fp8 in a uint2) ----
__device__ __forceinline__ void dec8(const uint2 b, float* f) {
    v2f f0 = __builtin_amdgcn_cvt_pk_f32_fp8(b.x, false);
    v2f f1 = __builtin_amdgcn_cvt_pk_f32_fp8(b.x, true);
    v2f f2 = __builtin_amdgcn_cvt_pk_f32_fp8(b.y, false);
    v2f f3 = __builtin_amdgcn_cvt_pk_f32_fp8(b.y, true);
    f[0] = f0.x; f[1] = f0.y; f[2] = f1.x; f[3] = f1.y;
    f[4] = f2.x; f[5] = f2.y; f[6] = f3.x; f[7] = f3.y;
}
// packed-fma variant: a[4] are float2 accumulators -> v_pk_fma_f32
__device__ __forceinline__ void fma8p(const uint2 b, const float v, v2f* a) {
    v2f f0 = __builtin_amdgcn_cvt_pk_f32_fp8(b.x, false);
    v2f f1 = __builtin_amdgcn_cvt_pk_f32_fp8(b.x, true);
    v2f f2 = __builtin_amdgcn_cvt_pk_f32_fp8(b.y, false);
    v2f f3 = __builtin_amdgcn_cvt_pk_f32_fp8(b.y, true);
    const v2f vv = {v, v};
    a[0] += vv * f0;
    a[1] += vv * f1;
    a[2] += vv * f2;
    a[3] += vv * f3;
}
__device__ __forceinline__ uint2 pack_fp8x8(const float* a) {
    int lo = 0, hi = 0;
    lo = __builtin_amdgcn_cvt_pk_fp8_f32(a[0], a[1], lo, false);
    lo = __builtin_amdgcn_cvt_pk_fp8_f32(a[2], a[3], lo, true);
    hi = __builtin_amdgcn_cvt_pk_fp8_f32(a[4], a[5], hi, false);
    hi = __builtin_amdgcn_cvt_pk_fp8_f32(a[6], a[7], hi, true);
    return make_uint2((unsigned)lo, (unsigned)hi);
}

// fp32 table -> fp8 table, scaled by FP8_SCALE. One thread = 8 features.
__global__ void __launch_bounds__(256) cvt8_kernel(
    const float4* __restrict__ src, uint2* __restrict__ dst, int n8) {
    int t = blockIdx.x * blockDim.x + threadIdx.x;
    if (t < n8) {
        float4 a = src[2 * t], b = src[2 * t + 1];
        float f[8] = {a.x * FP8_SCALE, a.y * FP8_SCALE, a.z * FP8_SCALE, a.w * FP8_SCALE,
                      b.x * FP8_SCALE, b.y * FP8_SCALE, b.z * FP8_SCALE, b.w * FP8_SCALE};
        dst[t] = pack_fp8x8(f);
    }
}

// ---------- two-level binned counting sort ----------

__global__ void __launch_bounds__(256) coarse_hist(
    const int4* __restrict__ eu4, const int4* __restrict__ ei4,
    int* __restrict__ coarseCnt) {
    __shared__ int lc[NBK];
    const int t = threadIdx.x;
    for (int j = t; j < NBK; j += 256) lc[j] = 0;
    __syncthreads();
    for (int k = blockIdx.x * 256 + t; k < NEDGE / 4; k += HIST_GRID * 256) {
        int4 u = eu4[k];
        int4 i = ei4[k];
        atomicAdd(&lc[u.x >> USH], 1); atomicAdd(&lc[u.y >> USH], 1);
        atomicAdd(&lc[u.z >> USH], 1); atomicAdd(&lc[u.w >> USH], 1);
        atomicAdd(&lc[UBK + (i.x >> ISH)], 1); atomicAdd(&lc[UBK + (i.y >> ISH)], 1);
        atomicAdd(&lc[UBK + (i.z >> ISH)], 1); atomicAdd(&lc[UBK + (i.w >> ISH)], 1);
    }
    __syncthreads();
    for (int j = t; j < NBK; j += 256)
        if (lc[j]) atomicAdd(&coarseCnt[j * CPAD], lc[j]);
}

__global__ void __launch_bounds__(512) coarse_scan(
    const int* __restrict__ cnt, int* __restrict__ base, int* __restrict__ cur) {
    __shared__ int a[512];
    const int t = threadIdx.x;
    int v = (t < UBK) ? cnt[t * CPAD] : 0;
    a[t] = v;
    __syncthreads();
    for (int off = 1; off < 512; off <<= 1) {
        int x = (t >= off) ? a[t - off] : 0;
        __syncthreads();
        a[t] += x;
        __syncthreads();
    }
    if (t < UBK) { base[t] = a[t] - v; cur[t * CPAD] = a[t] - v; }
    __syncthreads();
    v = (t < IBK) ? cnt[(UBK + t) * CPAD] : 0;
    a[t] = v;
    __syncthreads();
    for (int off = 1; off < 512; off <<= 1) {
        int x = (t >= off) ? a[t - off] : 0;
        __syncthreads();
        a[t] += x;
        __syncthreads();
    }
    if (t < IBK) { base[UBK + t] = a[t] - v; cur[(UBK + t) * CPAD] = a[t] - v; }
}

// binA: block-level LDS counting sort per (tile, direction). Payload is built
// and sorted entirely in LDS, then flushed sequentially so global writes are
// wave-coalesced full lines. ATILE=4096 -> 40960B LDS -> exactly 4 blocks/CU.
// blockIdx.y: 0 = U-direction, 1 = I-direction.
__global__ void __launch_bounds__(256, 4) binA(
    const int* __restrict__ eu, const int* __restrict__ ei,
    const float* __restrict__ ev,
    int* __restrict__ ccur,           // padded cursors, NBK*CPAD
    int2* __restrict__ stU, int2* __restrict__ stI) {
    __shared__ int2 pay[ATILE];             // 32 KB sorted payload
    __shared__ unsigned char sbid[ATILE];   // 4 KB bucket id per slot
    __shared__ int hist[256];
    __shared__ int pscan[256];
    __shared__ int cursor[256];
    __shared__ int delta[256];

    const int t = threadIdx.x;
    const int dirI = blockIdx.y;
    const int tb = blockIdx.x * ATILE;
    const int n = min(ATILE, NEDGE - tb);
    const int* key = dirI ? ei : eu;
    const int SH = dirI ? ISH : USH;

    hist[t] = 0;
    __syncthreads();
    for (int k = t; k < n; k += 256)
        atomicAdd(&hist[key[tb + k] >> SH], 1);
    __syncthreads();
    pscan[t] = hist[t];
    __syncthreads();
    for (int off = 1; off < 256; off <<= 1) {
        int x = (t >= off) ? pscan[t - off] : 0;
        __syncthreads();
        pscan[t] += x;
        __syncthreads();
    }
    {
        const int c = hist[t];
        const int lst = pscan[t] - c;
        cursor[t] = lst;
        int gp = 0;
        if (c > 0) {
            int* gc = dirI ? (ccur + UBK * CPAD) : ccur;
            gp = atomicAdd(&gc[t * CPAD], c);
        }
        delta[t] = gp - lst;
    }
    __syncthreads();
    // scatter payload into sorted LDS slots; edge stream read is linear
    if (dirI == 0) {
        for (int k = t; k < n; k += 256) {
            const int e = tb + k;
            const int u = eu[e], i = ei[e];
            const int b = u >> USH;
            const int p = atomicAdd(&cursor[b], 1);
            pay[p] = make_int2(((u & ((1 << USH) - 1)) << 16) | i,
                               __float_as_int(ev[e]));
            sbid[p] = (unsigned char)b;
        }
    } else {
        for (int k = t; k < n; k += 256) {
            const int e = tb + k;
            const int u = eu[e], i = ei[e];
            const int b = i >> ISH;
            const int p = atomicAdd(&cursor[b], 1);
            pay[p] = make_int2(((i & ((1 << ISH) - 1)) << 17) | u,
                               __float_as_int(ev[e]));
            sbid[p] = (unsigned char)b;
        }
    }
    __syncthreads();
    // sequential flush: consecutive threads -> consecutive global addresses
    int2* st = dirI ? stI : stU;
    for (int p = t; p < n; p += 256)
        st[delta[sbid[p]] + p] = pay[p];
}

// binB: fine sort within each coarse bucket. Item branch keeps the R6
// source-split key (local_item<<1)|(u>=UHALF); rpIm = mid pointer. Final
// placement scatters into a 72KB LDS staging buffer then flushes
// sequentially (coalesced full-line writes). Fallback to direct scatter if
// a bucket exceeds BCAP (+16 sigma; data-dependent only, capture-safe).
__global__ void __launch_bounds__(256) binB(
    const int2* __restrict__ stU, const int2* __restrict__ stI,
    const int* __restrict__ base, const int* __restrict__ cnt,
    int* __restrict__ rpU, int* __restrict__ rpI, int* __restrict__ rpIm,
    unsigned* __restrict__ ivU, unsigned* __restrict__ ivI) {
    __shared__ int h[512];
    __shared__ unsigned pay[BCAP];   // 72 KB
    const int t = threadIdx.x;
    const int b = blockIdx.x;
    if (b < UBK) {
        const int s = base[b], n = cnt[b * CPAD];
        const int dbase = b << USH;
        h[t] = 0; h[t + 256] = 0;
        __syncthreads();
        for (int p = s + t; p < s + n; p += 256)
            atomicAdd(&h[(unsigned)stU[p].x >> 16], 1);
        __syncthreads();
        const int o0 = h[t], o1 = h[t + 256];
        for (int off = 1; off < 512; off <<= 1) {
            int x0 = (t >= off) ? h[t - off] : 0;
            int x1 = (t + 256 >= off) ? h[t + 256 - off] : 0;
            __syncthreads();
            h[t] += x0; h[t + 256] += x1;
            __syncthreads();
        }
        const int e0 = h[t] - o0, e1 = h[t + 256] - o1;   // bucket-relative
        __syncthreads();
        h[t] = e0; h[t + 256] = e1;
        if (dbase + t < USER_NUM) rpU[dbase + t] = s + e0;
        if (dbase + 256 + t < USER_NUM) rpU[dbase + 256 + t] = s + e1;
        if (t == 0 && dbase + 512 >= USER_NUM) rpU[USER_NUM] = s + n;
        __syncthreads();
        if (n <= BCAP) {
            for (int p = s + t; p < s + n; p += 256) {
                int2 en = stU[p];
                unsigned x = (unsigned)en.x;
                int pos = atomicAdd(&h[x >> 16], 1);
                unsigned bf = roundbf((unsigned)en.y);
                pay[pos] = (bf << 16) | (x & 0xFFFFu);
            }
            __syncthreads();
            for (int k = t; k < n; k += 256) ivU[s + k] = pay[k];
        } else {
            for (int p = s + t; p < s + n; p += 256) {
                int2 en = stU[p];
                unsigned x = (unsigned)en.x;
                int pos = atomicAdd(&h[x >> 16], 1);
                unsigned bf = roundbf((unsigned)en.y);
                ivU[s + pos] = (bf << 16) | (x & 0xFFFFu);
            }
        }
    } else {
        const int ib = b - UBK;
        const int s = base[b], n = cnt[b * CPAD];
        const int dbase = ib << ISH;
        h[t] = 0; h[t + 256] = 0;
        __syncthreads();
        for (int p = s + t; p < s + n; p += 256) {
            unsigned x = (unsigned)stI[p].x;
            const int c = (int)((x >> 17) << 1) | (((x & 0x1FFFFu) >= UHALF) ? 1 : 0);
            atomicAdd(&h[c], 1);
        }
        __syncthreads();
        // counts of my interleaved pair (row t: counters 2t, 2t+1)
        const int c0 = h[2 * t], c1 = h[2 * t + 1];
        // inclusive scan over 512 linear slots (thread owns slots t, t+256);
        // linear order == final layout order (row-major, half0 then half1)
        for (int off = 1; off < 512; off <<= 1) {
            int x0 = (t >= off) ? h[t - off] : 0;
            int x1 = (t + 256 >= off) ? h[t + 256 - off] : 0;
            __syncthreads();
            h[t] += x0; h[t + 256] += x1;
            __syncthreads();
        }
        const int incl0 = h[2 * t], incl1 = h[2 * t + 1];
        const int st0 = incl0 - c0;      // bucket-relative half0 start
        const int st1 = incl1 - c1;      // bucket-relative half1 start
        __syncthreads();
        h[2 * t] = st0; h[2 * t + 1] = st1;  // cursors for scatter
        if (dbase + t < ITEM_NUM) { rpI[dbase + t] = s + st0; rpIm[dbase + t] = s + st1; }
        if (t == 0 && dbase + 256 >= ITEM_NUM) rpI[ITEM_NUM] = s + n;
        __syncthreads();
        if (n <= BCAP) {
            for (int p = s + t; p < s + n; p += 256) {
                int2 en = stI[p];
                unsigned x = (unsigned)en.x;
                const int c = (int)((x >> 17) << 1) | (((x & 0x1FFFFu) >= UHALF) ? 1 : 0);
                int pos = atomicAdd(&h[c], 1);
                unsigned v15 = roundbf((unsigned)en.y) & 0x7FFFu;
                pay[pos] = (v15 << 17) | (x & 0x1FFFFu);
            }
            __syncthreads();
            for (int k = t; k < n; k += 256) ivI[s + k] = pay[k];
        } else {
            for (int p = s + t; p < s + n; p += 256) {
                int2 en = stI[p];
                unsigned x = (unsigned)en.x;
                const int c = (int)((x >> 17) << 1) | (((x & 0x1FFFFu) >= UHALF) ? 1 : 0);
                int pos = atomicAdd(&h[c], 1);
                unsigned v15 = roundbf((unsigned)en.y) & 0x7FFFu;
                ivI[s + pos] = (v15 << 17) | (x & 0x1FFFFu);
            }
        }
    }
}

// ---------- gather hop core ----------
// sub-owns-row layout: each 8-lane sub-group processes ONE full row (lane r
// holds features 8r..8r+7), a wave covers 8 consecutive rows.
// R14: hop blocks are 2 WAVES (128 threads) instead of 4 -> block retirement
// granularity halves. With 4-wave blocks a straggler wave pinned 3 finished
// wave slots + 16KB LDS until block retirement (the 45% occupancy signal);
// with 2-wave blocks at most 1 slot idles. 16 blocks/CU x 2 waves = full
// 32-wave residency; LDS 16 x 8KB = 128KB <= 160KB.
// (a) each wave cooperatively stages its rows' contiguous iv range into LDS;
// (b) item waves run FIRST (2x work per row -> longest-first drain);
// (c) I-direction rows run as two ranges (u<UHALF, u>=UHALF) for L2 fit.
#define UW (USER_NUM / 8)   // 12500 user waves
#define IW (ITEM_NUM / 8)   // 6250 item waves

template<bool ISU>
__device__ __forceinline__ int xof(unsigned q) {
    return ISU ? (int)(q & 0xFFFFu) : (int)(q & 0x1FFFFu);
}
template<bool ISU>
__device__ __forceinline__ float vof(unsigned q) {
    return ISU ? __uint_as_float(q & 0xFFFF0000u)
               : __uint_as_float((q >> 17) << 16);
}

template<bool ISU, int N>
__device__ __forceinline__ void edge_block(
    const unsigned* __restrict__ iv, int t,
    const uint2* __restrict__ srcr, v2f* a0, v2f* a1) {
    unsigned q[N];
    uint2 b[N];
#pragma unroll
    for (int j = 0; j < N; j++) q[j] = iv[t + j];
#pragma unroll
    for (int j = 0; j < N; j++) b[j] = srcr[xof<ISU>(q[j]) * 8];
#pragma unroll
    for (int j = 0; j < N; j++) fma8p(b[j], vof<ISU>(q[j]), (j & 1) ? a1 : a0);
}

template<bool ISU>
__device__ __forceinline__ void accum_range(
    const unsigned* __restrict__ iv, const uint2* __restrict__ srcr,
    int s, int e2, v2f* a0, v2f* a1) {
    int t = s;
    for (; t + 15 < e2; t += 16) edge_block<ISU, 16>(iv, t, srcr, a0, a1);
    if (t + 7 < e2) { edge_block<ISU, 8>(iv, t, srcr, a0, a1); t += 8; }
    if (t + 3 < e2) { edge_block<ISU, 4>(iv, t, srcr, a0, a1); t += 4; }
    if (t + 1 < e2) { edge_block<ISU, 2>(iv, t, srcr, a0, a1); t += 2; }
    if (t < e2)     edge_block<ISU, 1>(iv, t, srcr, a0, a1);
}

__device__ __forceinline__ void acc_combine(const v2f* a0, const v2f* a1, float* acc) {
#pragma unroll
    for (int k = 0; k < 4; k++) {
        const v2f sv = a0[k] + a1[k];
        acc[2 * k]     = sv.x;
        acc[2 * k + 1] = sv.y;
    }
}

__global__ void __launch_bounds__(128) gather_hop_f8(
    const int* __restrict__ rpU, const unsigned* __restrict__ ivU,
    const uint2* __restrict__ srcForU, uint2* __restrict__ outU,
    const int* __restrict__ rpI, const int* __restrict__ rpIm,
    const unsigned* __restrict__ ivI,
    const uint2* __restrict__ srcForI, uint2* __restrict__ outI) {
    __shared__ unsigned sIv[2][IVCAP];
    const int wslot = threadIdx.x >> 6;
    const int lane = threadIdx.x & 63;
    const int sub = lane >> 3;
    const int r = lane & 7;
    const int wave = blockIdx.x * 2 + wslot;
    const bool active = wave < UW + IW;
    const bool isI = wave < IW;                 // item-first
    int rowBase = 0;
    const int* rp = rpU; const unsigned* ivg = ivU;
    if (active) {
        rowBase = isI ? wave * 8 : (wave - IW) * 8;
        rp  = isI ? rpI : rpU;
        ivg = isI ? ivI : ivU;
    }
    int sB = 0, eB = 0;
    if (active) { sB = rp[rowBase]; eB = rp[rowBase + 8]; }
    unsigned* buf = sIv[wslot];
    const int nst = min(eB - sB, IVCAP);
    for (int k = lane; k < nst; k += 64) buf[k] = ivg[sB + k];
    __syncthreads();
    if (!active) return;
    const int row = rowBase + sub;
    const int sr = rp[row], er = rp[row + 1];
    float acc[8];
    v2f a0[4] = {{0.f,0.f},{0.f,0.f},{0.f,0.f},{0.f,0.f}};
    v2f a1[4] = {{0.f,0.f},{0.f,0.f},{0.f,0.f},{0.f,0.f}};
    if (eB - sB <= IVCAP) {
        const unsigned* p = buf - sB;           // LDS-backed, ds_read path
        if (isI) {
            const int mr = rpIm[row];
            const uint2* srcr = srcForI + r;
            accum_range<false>(p, srcr, sr, mr, a0, a1);
            accum_range<false>(p, srcr, mr, er, a0, a1);
        } else {
            accum_range<true>(p, srcForU + r, sr, er, a0, a1);
        }
    } else {                                     // overflow fallback (never hot)
        if (isI) {
            const int mr = rpIm[row];
            const uint2* srcr = srcForI + r;
            accum_range<false>(ivg, srcr, sr, mr, a0, a1);
            accum_range<false>(ivg, srcr, mr, er, a0, a1);
        } else {
            accum_range<true>(ivg, srcForU + r, sr, er, a0, a1);
        }
    }
    acc_combine(a0, a1, acc);
    if (isI) outI[row * 8 + r] = pack_fp8x8(acc);
    else     outU[row * 8 + r] = pack_fp8x8(acc);
}

// hop3 with fused self-distillation loss (same staging + item-first).
__global__ void __launch_bounds__(128) gather_hop3(
    const int* __restrict__ rpU, const unsigned* __restrict__ ivU,
    const uint2* __restrict__ srcForU,
    const int* __restrict__ rpI, const int* __restrict__ rpIm,
    const unsigned* __restrict__ ivI, const uint2* __restrict__ srcForI,
    const float4* __restrict__ embU, const uint2* __restrict__ g1u,
    const uint2* __restrict__ g2u, float4* __restrict__ gcnU,
    const float4* __restrict__ embI, const uint2* __restrict__ g1i,
    const uint2* __restrict__ g2i, float4* __restrict__ gcnI,
    const float4* __restrict__ oldU4, const float4* __restrict__ oldI4,
    const float* __restrict__ nU, const float* __restrict__ nI,
    float* __restrict__ accs) {
    __shared__ unsigned sIv[2][IVCAP];
    const int wslot = threadIdx.x >> 6;
    const int lane = threadIdx.x & 63;
    const int sub = lane >> 3;
    const int r = lane & 7;
    const int wave = blockIdx.x * 2 + wslot;
    const bool active = wave < UW + IW;
    const bool isI = wave < IW;                 // item-first
    int rowBase = 0;
    const int* rp = rpU; const unsigned* ivg = ivU;
    if (active) {
        rowBase = isI ? wave * 8 : (wave - IW) * 8;
        rp  = isI ? rpI : rpU;
        ivg = isI ? ivI : ivU;
    }
    int sB = 0, eB = 0;
    if (active) { sB = rp[rowBase]; eB = rp[rowBase + 8]; }
    unsigned* buf = sIv[wslot];
    const int nst = min(eB - sB, IVCAP);
    for (int k = lane; k < nst; k += 64) buf[k] = ivg[sB + k];
    __syncthreads();
    if (!active) return;
    const int row = rowBase + sub;
    const int sr = rp[row], er = rp[row + 1];
    float acc[8];
    v2f a0[4] = {{0.f,0.f},{0.f,0.f},{0.f,0.f},{0.f,0.f}};
    v2f a1[4] = {{0.f,0.f},{0.f,0.f},{0.f,0.f},{0.f,0.f}};
    if (eB - sB <= IVCAP) {
        const unsigned* p = buf - sB;
        if (isI) {
            const int mr = rpIm[row];
            const uint2* srcr = srcForI + r;
            accum_range<false>(p, srcr, sr, mr, a0, a1);
            accum_range<false>(p, srcr, mr, er, a0, a1);
        } else {
            accum_range<true>(p, srcForU + r, sr, er, a0, a1);
        }
    } else {
        if (isI) {
            const int mr = rpIm[row];
            const uint2* srcr = srcForI + r;
            accum_range<false>(ivg, srcr, sr, mr, a0, a1);
            accum_range<false>(ivg, srcr, mr, er, a0, a1);
        } else {
            accum_range<true>(ivg, srcForU + r, sr, er, a0, a1);
        }
    }
    acc_combine(a0, a1, acc);
    {
        const float C1 = 0.5f / FP8_SCALE;
        const float C2 = (1.0f / 3.0f) / FP8_SCALE;
        const float C3 = 0.25f / FP8_SCALE;
        const float4* emb  = isI ? embI : embU;
        const uint2*  g1   = isI ? g1i  : g1u;
        const uint2*  g2   = isI ? g2i  : g2u;
        float4*       gcn  = isI ? gcnI : gcnU;
        const float4* old4 = isI ? oldI4 : oldU4;
        const float*  nrm  = isI ? nI   : nU;
        float f1[8], f2[8];
        dec8(g1[row * 8 + r], f1);
        dec8(g2[row * 8 + r], f2);
        const float4 e0 = emb[row * 16 + 2 * r];
        const float4 e1 = emb[row * 16 + 2 * r + 1];
        float4 o0, o1;
        o0.x = e0.x + C1 * f1[0] + C2 * f2[0] + C3 * acc[0];
        o0.y = e0.y + C1 * f1[1] + C2 * f2[1] + C3 * acc[1];
        o0.z = e0.z + C1 * f1[2] + C2 * f2[2] + C3 * acc[2];
        o0.w = e0.w + C1 * f1[3] + C2 * f2[3] + C3 * acc[3];
        o1.x = e1.x + C1 * f1[4] + C2 * f2[4] + C3 * acc[4];
        o1.y = e1.y + C1 * f1[5] + C2 * f2[5] + C3 * acc[5];
        o1.z = e1.z + C1 * f1[6] + C2 * f2[6] + C3 * acc[6];
        o1.w = e1.w + C1 * f1[7] + C2 * f2[7] + C3 * acc[7];
        gcn[row * 16 + 2 * r] = o0;
        gcn[row * 16 + 2 * r + 1] = o1;
        // ---- fused self-distillation loss ----
        const float4 d0 = old4[row * 16 + 2 * r];
        const float4 d1 = old4[row * 16 + 2 * r + 1];
        const float ex = d0.x - o0.x, ey = d0.y - o0.y;
        const float ez = d0.z - o0.z, ew = d0.w - o0.w;
        const float fx = d1.x - o1.x, fy = d1.y - o1.y;
        const float fz = d1.z - o1.z, fw = d1.w - o1.w;
        float ss = ex * ex + ey * ey + ez * ez + ew * ew
                 + fx * fx + fy * fy + fz * fz + fw * fw;
        ss += __shfl_xor(ss, 1, 64);
        ss += __shfl_xor(ss, 2, 64);
        ss += __shfl_xor(ss, 4, 64);
        float val = (r == 0) ? sqrtf(ss) * nrm[row] : 0.0f;
        val = waveReduceSum(val);
        if (lane == 0) {
            const int slot = wave & (NSLOT - 1);
            unsafeAtomicAdd(&accs[(isI ? 3 : 2) * NSLOT + slot], val);
        }
    }
}

// ---------- losses ----------
__global__ void __launch_bounds__(256) bpr_loss(
    const int* __restrict__ user, const int* __restrict__ itemI,
    const int* __restrict__ itemJ,
    const float4* __restrict__ gcnU4, const float4* __restrict__ gcnI4,
    float* __restrict__ accs) {
    const int lane = threadIdx.x & 63;
    const int sub = lane >> 4;
    const int r = lane & 15;
    const int W = blockIdx.x * 4 + (threadIdx.x >> 6);
    const int NW = gridDim.x * 4;
    float accB = 0.0f, accR = 0.0f;
    for (int g = W; g < NB / 4; g += NW) {
        const int samp = g * 4 + sub;
        const int uu = user[samp], vi = itemI[samp], vj = itemJ[samp];
        const float4 u  = gcnU4[uu * 16 + r];
        const float4 xi = gcnI4[vi * 16 + r];
        const float4 xj = gcnI4[vj * 16 + r];
        float pi = u.x * xi.x + u.y * xi.y + u.z * xi.z + u.w * xi.w;
        float pj = u.x * xj.x + u.y * xj.y + u.z * xj.z + u.w * xj.w;
        float rg = u.x * u.x + u.y * u.y + u.z * u.z + u.w * u.w
                 + xi.x * xi.x + xi.y * xi.y + xi.z * xi.z + xi.w * xi.w
                 + xj.x * xj.x + xj.y * xj.y + xj.z * xj.z + xj.w * xj.w;
#pragma unroll
        for (int off = 1; off <= 8; off <<= 1) {
            pi += __shfl_xor(pi, off, 64);
            pj += __shfl_xor(pj, off, 64);
            rg += __shfl_xor(rg, off, 64);
        }
        if (r == 0) {
            const float x = pi - pj;
            accB += fmaxf(-x, 0.0f) + log1pf(expf(-fabsf(x)));
            accR += rg;
        }
    }
    accB = waveReduceSum(accB);
    accR = waveReduceSum(accR);
    if (lane == 0) {
        const int slot = W & (NSLOT - 1);
        unsafeAtomicAdd(&accs[0 * NSLOT + slot], accB);
        unsafeAtomicAdd(&accs[1 * NSLOT + slot], accR);
    }
}

__global__ void __launch_bounds__(64) finalize(const float* __restrict__ accs,
                                               float* __restrict__ out) {
    const int lane = threadIdx.x;
    float s[4];
#pragma unroll
    for (int k = 0; k < 4; k++) {
        float v = 0.0f;
        for (int j = lane; j < NSLOT; j += 64) v += accs[k * NSLOT + j];
        s[k] = waveReduceSum(v);
    }
    if (lane == 0) {
        const float loss_bpr = s[0] / NB + 1e-4f * (s[1] / NB);
        const float loss_self = s[2] / USER_NUM + s[3] / ITEM_NUM;
        out[0] = loss_bpr;
        out[1] = 100.0f * loss_self;
        out[2] = 1.0f;
        out[3] = 1.0f;
    }
}

extern "C" void kernel_launch(void* const* d_in, const int* in_sizes, int n_in,
                              void* d_out, int out_size, void* d_ws, size_t ws_size,
                              hipStream_t stream) {
    const int*   user     = (const int*)d_in[0];
    const int*   item_i   = (const int*)d_in[1];
    const int*   item_j   = (const int*)d_in[2];
    const int*   edge_u   = (const int*)d_in[3];
    const int*   edge_i   = (const int*)d_in[4];
    const float* edge_val = (const float*)d_in[5];
    const float* user_emb = (const float*)d_in[6];
    const float* item_emb = (const float*)d_in[7];
    const float* old_U    = (const float*)d_in[8];
    const float* old_I    = (const float*)d_in[9];
    const float* n_U      = (const float*)d_in[10];
    const float* n_I      = (const float*)d_in[11];
    float* out = (float*)d_out;

    char* base = (char*)d_ws;
    size_t off = 0;
    auto carve = [&](size_t bytes) {
        char* p = base + off;
        off += (bytes + 255) & ~(size_t)255;
        return p;
    };
    int*      coarseCnt = (int*)carve(NBK * CPAD * 4);  // padded: 1 count / 64B
    float*    accs      = (float*)carve(4 * NSLOT * 4);
    size_t zero_bytes = off;  // everything above must start zeroed
    int*      cbase = (int*)carve(NBK * 4);             // compact
    int*      ccur  = (int*)carve(NBK * CPAD * 4);      // padded cursors
    int*      rpU   = (int*)carve((USER_NUM + 1) * 4);
    int*      rpI   = (int*)carve((ITEM_NUM + 1) * 4);
    int*      rpIm  = (int*)carve((ITEM_NUM + 1) * 4);
    unsigned* ivU   = (unsigned*)carve((size_t)NEDGE * 4);
    unsigned* ivI   = (unsigned*)carve((size_t)NEDGE * 4);
    uint2*    ebU8  = (uint2*)carve((size_t)USER_NUM * DD);  // fp8 tables
    uint2*    ebI8  = (uint2*)carve((size_t)ITEM_NUM * DD);
    uint2*    g1u8  = (uint2*)carve((size_t)USER_NUM * DD);
    uint2*    g1i8  = (uint2*)carve((size_t)ITEM_NUM * DD);
    uint2*    g2u8  = (uint2*)carve((size_t)USER_NUM * DD);
    uint2*    g2i8  = (uint2*)carve((size_t)ITEM_NUM * DD);
    int2*     stU   = (int2*)carve((size_t)NEDGE * 8);   // staging, dead after binB
    int2*     stI   = (int2*)carve((size_t)NEDGE * 8);
    float* gcnU = (float*)stU;   // aliases staging (hop3 runs after binB)
    float* gcnI = (float*)stI;

    hipMemsetAsync(d_ws, 0, zero_bytes, stream);

    const dim3 blk(256);
    const dim3 blk2(128);

    cvt8_kernel<<<(USER_NUM * 8 + 255) / 256, blk, 0, stream>>>(
        (const float4*)user_emb, ebU8, USER_NUM * 8);
    cvt8_kernel<<<(ITEM_NUM * 8 + 255) / 256, blk, 0, stream>>>(
        (const float4*)item_emb, ebI8, ITEM_NUM * 8);

    coarse_hist<<<HIST_GRID, blk, 0, stream>>>((const int4*)edge_u,
                                               (const int4*)edge_i, coarseCnt);
    coarse_scan<<<1, 512, 0, stream>>>(coarseCnt, cbase, ccur);
    binA<<<dim3(NTILE, 2), blk, 0, stream>>>(edge_u, edge_i, edge_val,
                                             ccur, stU, stI);
    binB<<<NBK, blk, 0, stream>>>(stU, stI, cbase, coarseCnt,
                                  rpU, rpI, rpIm, ivU, ivI);

    const int hop_waves = UW + IW;                 // 18750
    const int hop_grid = (hop_waves + 1) / 2;      // 9375

    gather_hop_f8<<<hop_grid, blk2, 0, stream>>>(rpU, ivU, ebI8, g1u8,
                                                 rpI, rpIm, ivI, ebU8, g1i8);
    gather_hop_f8<<<hop_grid, blk2, 0, stream>>>(rpU, ivU, g1i8, g2u8,
                                                 rpI, rpIm, ivI, g1u8, g2i8);
    gather_hop3<<<hop_grid, blk2, 0, stream>>>(
        rpU, ivU, g2i8, rpI, rpIm, ivI, g2u8,
        (const float4*)user_emb, g1u8, g2u8, (float4*)gcnU,
        (const float4*)item_emb, g1i8, g2i8, (float4*)gcnI,
        (const float4*)old_U, (const float4*)old_I, n_U, n_I, accs);

    bpr_loss<<<128, blk, 0, stream>>>(user, item_i, item_j,
                                      (const float4*)gcnU, (const float4*)gcnI, accs);
    finalize<<<1, 64, 0, stream>>>(accs, out);
}